// Round 1
// baseline (685.147 us; speedup 1.0000x reference)
//
#include <hip/hip_runtime.h>
#include <cstdint>

#define D 128
#define LNUM 3

// ---------------- CSR construction ----------------

__global__ void hist_k(const int* __restrict__ dst, int* __restrict__ cnt, int E) {
    int e = blockIdx.x * blockDim.x + threadIdx.x;
    if (e < E) atomicAdd(&cnt[dst[e]], 1);
}

__global__ __launch_bounds__(1024) void scan_k(const int* __restrict__ cnt, int* __restrict__ rowptr, int N) {
    __shared__ int sh[1024];
    int t = threadIdx.x;
    int chunk = (N + 1023) >> 10;
    int b = t * chunk;
    int e = min(b + chunk, N);
    int s = 0;
    for (int i = b; i < e; ++i) s += cnt[i];
    sh[t] = s;
    __syncthreads();
    for (int off = 1; off < 1024; off <<= 1) {
        int v = (t >= off) ? sh[t - off] : 0;
        __syncthreads();
        sh[t] += v;
        __syncthreads();
    }
    int run = sh[t] - s;  // exclusive
    for (int i = b; i < e; ++i) { rowptr[i] = run; run += cnt[i]; }
    if (t == 1023) rowptr[N] = sh[1023];
}

__global__ void fill_k(const int* __restrict__ src, const int* __restrict__ dst,
                       const int* __restrict__ rowptr, int* __restrict__ cnt,
                       int* __restrict__ colA, int* __restrict__ pos, int E) {
    int e = blockIdx.x * blockDim.x + threadIdx.x;
    if (e >= E) return;
    int d = dst[e];
    int p = atomicAdd(&cnt[d], 1);
    int q = rowptr[d] + p;
    colA[q] = src[e];
    pos[e] = q;
}

// ---------------- edge-attr contribution: v[l] = W_e[l] @ att_edge[l]; ec[l][e] = ea[e]·v[l] ----------------

__global__ void vcomp_k(const float* __restrict__ We, const float* __restrict__ ae, float* __restrict__ vbuf) {
    int l = blockIdx.x;
    int j = threadIdx.x;
    const float* Wrow = We + ((size_t)l * D + j) * D;
    const float* a = ae + (size_t)l * D;
    float s = 0.f;
    for (int d = 0; d < D; ++d) s += Wrow[d] * a[d];
    vbuf[l * D + j] = s;
}

// 8 lanes per edge; writes ec permuted to CSR slot order
__global__ __launch_bounds__(256) void ec_k(const float* __restrict__ ea, const float* __restrict__ vbuf,
                                            const int* __restrict__ pos, float* __restrict__ ecp, int E) {
    __shared__ float vs[3][D];
    int t = threadIdx.x;
    if (t < D) {
        vs[0][t] = vbuf[t];
        vs[1][t] = vbuf[D + t];
        vs[2][t] = vbuf[2 * D + t];
    }
    __syncthreads();
    int e = blockIdx.x * 32 + (t >> 3);
    int sub = t & 7;
    if (e >= E) return;
    const float* row = ea + (size_t)e * D + sub * 16;
    float p0 = 0.f, p1 = 0.f, p2 = 0.f;
#pragma unroll
    for (int i = 0; i < 4; ++i) {
        float4 v = *(const float4*)&row[i * 4];
        int c = sub * 16 + i * 4;
        p0 += v.x * vs[0][c] + v.y * vs[0][c + 1] + v.z * vs[0][c + 2] + v.w * vs[0][c + 3];
        p1 += v.x * vs[1][c] + v.y * vs[1][c + 1] + v.z * vs[1][c + 2] + v.w * vs[1][c + 3];
        p2 += v.x * vs[2][c] + v.y * vs[2][c + 1] + v.z * vs[2][c + 2] + v.w * vs[2][c + 3];
    }
#pragma unroll
    for (int off = 1; off < 8; off <<= 1) {
        p0 += __shfl_xor(p0, off);
        p1 += __shfl_xor(p1, off);
        p2 += __shfl_xor(p2, off);
    }
    if (sub == 0) {
        int q = pos[e];
        ecp[q] = p0;
        ecp[E + q] = p1;
        ecp[2 * (size_t)E + q] = p2;
    }
}

// ---------------- GEMM: C[N,128] = A[N,128] @ W[128,128] ----------------

__global__ __launch_bounds__(256) void gemm_k(const float* __restrict__ A, const float* __restrict__ W,
                                              float* __restrict__ C, int N) {
    __shared__ float As[64][D];
    __shared__ float Ws[D][64];
    int row0 = blockIdx.x * 64;
    int cb = blockIdx.y * 64;
    int t = threadIdx.x;
    // load A tile (64x128) = 2048 float4
#pragma unroll
    for (int it = 0; it < 8; ++it) {
        int idx = it * 256 + t;
        int r = idx >> 5;
        int c = (idx & 31) * 4;
        int gr = row0 + r;
        float4 v = make_float4(0.f, 0.f, 0.f, 0.f);
        if (gr < N) v = *(const float4*)&A[(size_t)gr * D + c];
        *(float4*)&As[r][c] = v;
    }
    // load W tile (128x64) = 2048 float4
#pragma unroll
    for (int it = 0; it < 8; ++it) {
        int idx = it * 256 + t;
        int r = idx >> 4;
        int c = (idx & 15) * 4;
        *(float4*)&Ws[r][c] = *(const float4*)&W[(size_t)r * D + cb + c];
    }
    __syncthreads();
    int r0 = (t >> 4) * 4;
    int c0 = (t & 15) * 4;
    float acc[4][4] = {};
    for (int k = 0; k < D; k += 4) {
        float4 av[4], wv[4];
#pragma unroll
        for (int i = 0; i < 4; ++i) av[i] = *(const float4*)&As[r0 + i][k];
#pragma unroll
        for (int kk = 0; kk < 4; ++kk) wv[kk] = *(const float4*)&Ws[k + kk][c0];
#pragma unroll
        for (int i = 0; i < 4; ++i) {
            float ai[4] = {av[i].x, av[i].y, av[i].z, av[i].w};
#pragma unroll
            for (int kk = 0; kk < 4; ++kk) {
                acc[i][0] += ai[kk] * wv[kk].x;
                acc[i][1] += ai[kk] * wv[kk].y;
                acc[i][2] += ai[kk] * wv[kk].z;
                acc[i][3] += ai[kk] * wv[kk].w;
            }
        }
    }
#pragma unroll
    for (int i = 0; i < 4; ++i) {
        int gr = row0 + r0 + i;
        if (gr < N) {
            float4 v = make_float4(acc[i][0], acc[i][1], acc[i][2], acc[i][3]);
            *(float4*)&C[(size_t)gr * D + cb + c0] = v;
        }
    }
}

// ---------------- per-node scalars hs = h·att_src, hd = h·att_dst ----------------

__global__ __launch_bounds__(256) void dots_k(const float* __restrict__ h, const float* __restrict__ as,
                                              const float* __restrict__ ad, float* __restrict__ hs,
                                              float* __restrict__ hd, int N) {
    int wid = (blockIdx.x * blockDim.x + threadIdx.x) >> 6;
    int lane = threadIdx.x & 63;
    if (wid >= N) return;
    float2 v = *(const float2*)&h[(size_t)wid * D + lane * 2];
    float2 a = *(const float2*)&as[lane * 2];
    float2 b = *(const float2*)&ad[lane * 2];
    float ps = v.x * a.x + v.y * a.y;
    float pd = v.x * b.x + v.y * b.y;
#pragma unroll
    for (int off = 32; off; off >>= 1) {
        ps += __shfl_xor(ps, off);
        pd += __shfl_xor(pd, off);
    }
    if (lane == 0) {
        hs[wid] = ps;
        hd[wid] = pd;
    }
}

// ---------------- fused attention softmax + aggregate + bias + LayerNorm (one wave per node) ----------------

__global__ __launch_bounds__(256) void node_k(const float* __restrict__ h, const float* __restrict__ hs,
                                              const float* __restrict__ hd, const float* __restrict__ ecp,
                                              const int* __restrict__ rowptr, const int* __restrict__ colA,
                                              const float* __restrict__ bias, const float* __restrict__ gamma,
                                              const float* __restrict__ beta, float* __restrict__ out, int N) {
    int wid = blockIdx.x * 4 + (threadIdx.x >> 6);
    int lane = threadIdx.x & 63;
    if (wid >= N) return;
    int beg = rowptr[wid];
    int end = rowptr[wid + 1];
    float hdi = hd[wid];
    float m = -1e30f, denom = 0.f, acc0 = 0.f, acc1 = 0.f, sumec = 0.f;
    for (int j = beg; j < end; ++j) {
        int s = colA[j];
        float ec = ecp[j];
        sumec += ec;
        float a = hs[s] + hdi + ec;
        a = a > 0.f ? a : 0.2f * a;
        float mn = fmaxf(m, a);
        float r = __expf(m - mn);
        float p = __expf(a - mn);
        denom = denom * r + p;
        acc0 = acc0 * r + p * h[(size_t)s * D + lane];
        acc1 = acc1 * r + p * h[(size_t)s * D + 64 + lane];
        m = mn;
    }
    // self loop (fill_value='mean': ec_self = mean of incoming raw ec)
    {
        int degi = end - beg;
        float ecs = degi > 0 ? sumec / (float)degi : 0.f;
        float a = hs[wid] + hdi + ecs;
        a = a > 0.f ? a : 0.2f * a;
        float mn = fmaxf(m, a);
        float r = __expf(m - mn);
        float p = __expf(a - mn);
        denom = denom * r + p;
        acc0 = acc0 * r + p * h[(size_t)wid * D + lane];
        acc1 = acc1 * r + p * h[(size_t)wid * D + 64 + lane];
        m = mn;
    }
    float inv = 1.f / denom;
    float o0 = acc0 * inv + bias[lane];
    float o1 = acc1 * inv + bias[64 + lane];
    // LayerNorm over 128 dims (2 per lane)
    float s1 = o0 + o1;
#pragma unroll
    for (int off = 32; off; off >>= 1) s1 += __shfl_xor(s1, off);
    float mean = s1 * (1.f / 128.f);
    float d0 = o0 - mean, d1 = o1 - mean;
    float s2 = d0 * d0 + d1 * d1;
#pragma unroll
    for (int off = 32; off; off >>= 1) s2 += __shfl_xor(s2, off);
    float var = s2 * (1.f / 128.f);
    float rstd = rsqrtf(var + 1e-5f);
    out[(size_t)wid * D + lane] = d0 * rstd * gamma[lane] + beta[lane];
    out[(size_t)wid * D + 64 + lane] = d1 * rstd * gamma[64 + lane] + beta[64 + lane];
}

// ---------------- launch ----------------

extern "C" void kernel_launch(void* const* d_in, const int* in_sizes, int n_in,
                              void* d_out, int out_size, void* d_ws, size_t ws_size,
                              hipStream_t stream) {
    const float* x = (const float*)d_in[0];
    const int* ei = (const int*)d_in[1];
    const float* ea = (const float*)d_in[2];
    const float* W = (const float*)d_in[3];
    const float* att_src = (const float*)d_in[4];
    const float* att_dst = (const float*)d_in[5];
    const float* We = (const float*)d_in[6];
    const float* att_edge = (const float*)d_in[7];
    const float* bias = (const float*)d_in[8];
    const float* gamma = (const float*)d_in[9];
    const float* beta = (const float*)d_in[10];

    int N = in_sizes[0] / D;
    int E = in_sizes[1] / 2;
    const int* srcA = ei;
    const int* dstA = ei + E;

    float* p = (float*)d_ws;
    float* hbuf = p;  p += (size_t)N * D;
    float* h1 = p;    p += (size_t)N * D;
    float* hsb = p;   p += N;
    float* hdb = p;   p += N;
    float* vbuf = p;  p += LNUM * D;
    float* ecp = p;   p += (size_t)LNUM * E;
    int* ip = (int*)p;
    int* rowptr = ip; ip += N + 1;
    int* cnt = ip;    ip += N;
    int* colA = ip;   ip += E;
    int* pos = ip;    ip += E;

    hipMemsetAsync(cnt, 0, sizeof(int) * N, stream);
    hist_k<<<(E + 255) / 256, 256, 0, stream>>>(dstA, cnt, E);
    scan_k<<<1, 1024, 0, stream>>>(cnt, rowptr, N);
    hipMemsetAsync(cnt, 0, sizeof(int) * N, stream);
    fill_k<<<(E + 255) / 256, 256, 0, stream>>>(srcA, dstA, rowptr, cnt, colA, pos, E);
    vcomp_k<<<LNUM, D, 0, stream>>>(We, att_edge, vbuf);
    ec_k<<<(E + 31) / 32, 256, 0, stream>>>(ea, vbuf, pos, ecp, E);

    const float* hin = x;
    for (int l = 0; l < LNUM; ++l) {
        gemm_k<<<dim3((N + 63) / 64, 2), 256, 0, stream>>>(hin, W + (size_t)l * D * D, h1, N);
        dots_k<<<(N + 3) / 4, 256, 0, stream>>>(h1, att_src + (size_t)l * D, att_dst + (size_t)l * D, hsb, hdb, N);
        float* outp = (l == LNUM - 1) ? (float*)d_out : hbuf;
        node_k<<<(N + 3) / 4, 256, 0, stream>>>(h1, hsb, hdb, ecp + (size_t)l * E, rowptr, colA,
                                                bias + (size_t)l * D, gamma + (size_t)l * D,
                                                beta + (size_t)l * D, outp, N);
        hin = hbuf;
    }
}

// Round 2
// 549.520 us; speedup vs baseline: 1.2468x; 1.2468x over previous
//
#include <hip/hip_runtime.h>
#include <cstdint>

#define D 128
#define LNUM 3

static __device__ __forceinline__ float wred_sum(float x) {
#pragma unroll
    for (int off = 32; off; off >>= 1) x += __shfl_xor(x, off);
    return x;
}
static __device__ __forceinline__ float wred_max(float x) {
#pragma unroll
    for (int off = 32; off; off >>= 1) x = fmaxf(x, __shfl_xor(x, off));
    return x;
}
static __device__ __forceinline__ uint32_t f2bf_rne(float x) {
    uint32_t u = __float_as_uint(x);
    uint32_t r = u + 0x7fffu + ((u >> 16) & 1u);
    return r >> 16;
}

// ---------------- CSR construction ----------------

__global__ void hist_k(const int* __restrict__ dst, int* __restrict__ cnt, int E) {
    int e = blockIdx.x * blockDim.x + threadIdx.x;
    if (e < E) atomicAdd(&cnt[dst[e]], 1);
}

__global__ __launch_bounds__(1024) void scan_k(const int* __restrict__ cnt, int* __restrict__ rowptr, int N) {
    __shared__ int sh[1024];
    int t = threadIdx.x;
    int chunk = (N + 1023) >> 10;
    int b = t * chunk;
    int e = min(b + chunk, N);
    int s = 0;
    for (int i = b; i < e; ++i) s += cnt[i];
    sh[t] = s;
    __syncthreads();
    for (int off = 1; off < 1024; off <<= 1) {
        int v = (t >= off) ? sh[t - off] : 0;
        __syncthreads();
        sh[t] += v;
        __syncthreads();
    }
    int run = sh[t] - s;  // exclusive
    for (int i = b; i < e; ++i) { rowptr[i] = run; run += cnt[i]; }
    if (t == 1023) rowptr[N] = sh[1023];
}

__global__ void fill_k(const int* __restrict__ src, const int* __restrict__ dst,
                       const int* __restrict__ rowptr, int* __restrict__ cnt,
                       int* __restrict__ colA, int* __restrict__ pos, int E) {
    int e = blockIdx.x * blockDim.x + threadIdx.x;
    if (e >= E) return;
    int d = dst[e];
    int p = atomicAdd(&cnt[d], 1);
    int q = rowptr[d] + p;
    colA[q] = src[e];
    pos[e] = q;
}

// ---------------- edge-attr contribution ----------------

__global__ void vcomp_k(const float* __restrict__ We, const float* __restrict__ ae, float* __restrict__ vbuf) {
    int l = blockIdx.x;
    int j = threadIdx.x;
    const float* Wrow = We + ((size_t)l * D + j) * D;
    const float* a = ae + (size_t)l * D;
    float s = 0.f;
    for (int d = 0; d < D; ++d) s += Wrow[d] * a[d];
    vbuf[l * D + j] = s;
}

__global__ __launch_bounds__(256) void ec_k(const float* __restrict__ ea, const float* __restrict__ vbuf,
                                            const int* __restrict__ pos, float* __restrict__ ecp, int E) {
    __shared__ float vs[3][D];
    int t = threadIdx.x;
    if (t < D) {
        vs[0][t] = vbuf[t];
        vs[1][t] = vbuf[D + t];
        vs[2][t] = vbuf[2 * D + t];
    }
    __syncthreads();
    int e = blockIdx.x * 32 + (t >> 3);
    int sub = t & 7;
    if (e >= E) return;
    const float* row = ea + (size_t)e * D + sub * 16;
    float p0 = 0.f, p1 = 0.f, p2 = 0.f;
#pragma unroll
    for (int i = 0; i < 4; ++i) {
        float4 v = *(const float4*)&row[i * 4];
        int c = sub * 16 + i * 4;
        p0 += v.x * vs[0][c] + v.y * vs[0][c + 1] + v.z * vs[0][c + 2] + v.w * vs[0][c + 3];
        p1 += v.x * vs[1][c] + v.y * vs[1][c + 1] + v.z * vs[1][c + 2] + v.w * vs[1][c + 3];
        p2 += v.x * vs[2][c] + v.y * vs[2][c + 1] + v.z * vs[2][c + 2] + v.w * vs[2][c + 3];
    }
#pragma unroll
    for (int off = 1; off < 8; off <<= 1) {
        p0 += __shfl_xor(p0, off);
        p1 += __shfl_xor(p1, off);
        p2 += __shfl_xor(p2, off);
    }
    if (sub == 0) {
        int q = pos[e];
        ecp[q] = p0;
        ecp[E + q] = p1;
        ecp[2 * (size_t)E + q] = p2;
    }
}

// ---------------- GEMM: hbf[N,128](bf16) = A[N,128](f32) @ W[128,128](f32) ----------------

__global__ __launch_bounds__(256) void gemm_k(const float* __restrict__ A, const float* __restrict__ W,
                                              uint16_t* __restrict__ hbf, int N) {
    __shared__ float As[64][D];
    __shared__ float Ws[D][64];
    int row0 = blockIdx.x * 64;
    int cb = blockIdx.y * 64;
    int t = threadIdx.x;
#pragma unroll
    for (int it = 0; it < 8; ++it) {
        int idx = it * 256 + t;
        int r = idx >> 5;
        int c = (idx & 31) * 4;
        int gr = row0 + r;
        float4 v = make_float4(0.f, 0.f, 0.f, 0.f);
        if (gr < N) v = *(const float4*)&A[(size_t)gr * D + c];
        *(float4*)&As[r][c] = v;
    }
#pragma unroll
    for (int it = 0; it < 8; ++it) {
        int idx = it * 256 + t;
        int r = idx >> 4;
        int c = (idx & 15) * 4;
        *(float4*)&Ws[r][c] = *(const float4*)&W[(size_t)r * D + cb + c];
    }
    __syncthreads();
    int r0 = (t >> 4) * 4;
    int c0 = (t & 15) * 4;
    float acc[4][4] = {};
    for (int k = 0; k < D; k += 4) {
        float4 av[4], wv[4];
#pragma unroll
        for (int i = 0; i < 4; ++i) av[i] = *(const float4*)&As[r0 + i][k];
#pragma unroll
        for (int kk = 0; kk < 4; ++kk) wv[kk] = *(const float4*)&Ws[k + kk][c0];
#pragma unroll
        for (int i = 0; i < 4; ++i) {
            float ai[4] = {av[i].x, av[i].y, av[i].z, av[i].w};
#pragma unroll
            for (int kk = 0; kk < 4; ++kk) {
                acc[i][0] += ai[kk] * wv[kk].x;
                acc[i][1] += ai[kk] * wv[kk].y;
                acc[i][2] += ai[kk] * wv[kk].z;
                acc[i][3] += ai[kk] * wv[kk].w;
            }
        }
    }
#pragma unroll
    for (int i = 0; i < 4; ++i) {
        int gr = row0 + r0 + i;
        if (gr < N) {
            uint32_t u0 = f2bf_rne(acc[i][0]) | (f2bf_rne(acc[i][1]) << 16);
            uint32_t u1 = f2bf_rne(acc[i][2]) | (f2bf_rne(acc[i][3]) << 16);
            uint2 st; st.x = u0; st.y = u1;
            *(uint2*)&hbf[(size_t)gr * D + cb + c0] = st;
        }
    }
}

// ---------------- per-node scalars hs = h·att_src, hd = h·att_dst (bf16 h) ----------------

__global__ __launch_bounds__(256) void dots_k(const uint32_t* __restrict__ hb, const float* __restrict__ as,
                                              const float* __restrict__ ad, float* __restrict__ hs,
                                              float* __restrict__ hd, int N) {
    int wid = (blockIdx.x * blockDim.x + threadIdx.x) >> 6;
    int lane = threadIdx.x & 63;
    if (wid >= N) return;
    uint32_t u = hb[(size_t)wid * 64 + lane];
    float f0 = __uint_as_float(u << 16);
    float f1 = __uint_as_float(u & 0xffff0000u);
    float2 a = *(const float2*)&as[lane * 2];
    float2 b = *(const float2*)&ad[lane * 2];
    float ps = f0 * a.x + f1 * a.y;
    float pd = f0 * b.x + f1 * b.y;
#pragma unroll
    for (int off = 32; off; off >>= 1) {
        ps += __shfl_xor(ps, off);
        pd += __shfl_xor(pd, off);
    }
    if (lane == 0) {
        hs[wid] = ps;
        hd[wid] = pd;
    }
}

// ---------------- fused softmax(parallel) + aggregate(bf16 gather) + bias + LayerNorm ----------------

__global__ __launch_bounds__(256) void node_k(const uint32_t* __restrict__ hb, const float* __restrict__ hs,
                                              const float* __restrict__ hd, const float* __restrict__ ecp,
                                              const int* __restrict__ rowptr, const int* __restrict__ colA,
                                              const float* __restrict__ bias, const float* __restrict__ gamma,
                                              const float* __restrict__ beta, float* __restrict__ out, int N) {
    __shared__ float s_al[4][66];
    __shared__ int s_co[4][66];
    int w = threadIdx.x >> 6;
    int lane = threadIdx.x & 63;
    int wid = blockIdx.x * 4 + w;
    if (wid >= N) return;
    int beg = rowptr[wid], end = rowptr[wid + 1];
    int deg = end - beg;
    float hdi = hd[wid];
    float hsi = hs[wid];
    float acc0 = 0.f, acc1 = 0.f;

    if (deg <= 63) {
        bool v = lane < deg;
        int col = v ? colA[beg + lane] : 0;
        float ec = v ? ecp[beg + lane] : 0.f;
        float a = v ? (hs[col] + hdi + ec) : -3e38f;
        a = a > 0.f ? a : 0.2f * a;
        float sumec = wred_sum(ec);
        float ecs = deg > 0 ? sumec / (float)deg : 0.f;
        float as_ = hsi + hdi + ecs;
        as_ = as_ > 0.f ? as_ : 0.2f * as_;
        float m = fmaxf(wred_max(a), as_);
        float p = __expf(a - m);       // 0 for invalid lanes
        float ps = __expf(as_ - m);
        float denom = wred_sum(p) + ps;
        float inv = 1.f / denom;
        s_al[w][lane] = p * inv;
        s_co[w][lane] = col;
        if (lane == 0) { s_al[w][deg] = ps * inv; s_co[w][deg] = wid; }
        __asm__ volatile("s_waitcnt lgkmcnt(0)" ::: "memory");
        int ne = deg + 1;
        int j = 0;
        for (; j + 2 <= ne; j += 2) {
            int c0 = s_co[w][j], c1 = s_co[w][j + 1];
            float a0 = s_al[w][j], a1 = s_al[w][j + 1];
            uint32_t b0 = hb[(size_t)c0 * 64 + lane];
            uint32_t b1 = hb[(size_t)c1 * 64 + lane];
            acc0 += a0 * __uint_as_float(b0 << 16);
            acc1 += a0 * __uint_as_float(b0 & 0xffff0000u);
            acc0 += a1 * __uint_as_float(b1 << 16);
            acc1 += a1 * __uint_as_float(b1 & 0xffff0000u);
        }
        if (j < ne) {
            int c0 = s_co[w][j];
            float a0 = s_al[w][j];
            uint32_t b0 = hb[(size_t)c0 * 64 + lane];
            acc0 += a0 * __uint_as_float(b0 << 16);
            acc1 += a0 * __uint_as_float(b0 & 0xffff0000u);
        }
    } else {
        // generic chunked online-softmax path (rare: deg > 63)
        float m = -3e38f, dsum = 0.f, sumec = 0.f;
        for (int base = 0; base < deg; base += 64) {
            int j = base + lane;
            bool v = j < deg;
            int col = v ? colA[beg + j] : 0;
            float ec = v ? ecp[beg + j] : 0.f;
            float a = v ? (hs[col] + hdi + ec) : -3e38f;
            a = a > 0.f ? a : 0.2f * a;
            sumec += wred_sum(ec);
            float cm = wred_max(a);
            float nm = fmaxf(m, cm);
            dsum = dsum * __expf(m - nm) + wred_sum(__expf(a - nm));
            m = nm;
        }
        float ecs = sumec / (float)deg;
        float as_ = hsi + hdi + ecs;
        as_ = as_ > 0.f ? as_ : 0.2f * as_;
        float nm = fmaxf(m, as_);
        dsum = dsum * __expf(m - nm) + __expf(as_ - nm);
        m = nm;
        float inv = 1.f / dsum;
        for (int base = 0; base < deg; base += 64) {
            int j = base + lane;
            bool v = j < deg;
            int col = v ? colA[beg + j] : 0;
            float ec = v ? ecp[beg + j] : 0.f;
            float a = v ? (hs[col] + hdi + ec) : -3e38f;
            a = a > 0.f ? a : 0.2f * a;
            __asm__ volatile("s_waitcnt lgkmcnt(0)" ::: "memory");
            s_al[w][lane] = __expf(a - m) * inv;
            s_co[w][lane] = col;
            __asm__ volatile("s_waitcnt lgkmcnt(0)" ::: "memory");
            int cnt = min(64, deg - base);
            for (int k = 0; k < cnt; ++k) {
                int c = s_co[w][k];
                float al = s_al[w][k];
                uint32_t b = hb[(size_t)c * 64 + lane];
                acc0 += al * __uint_as_float(b << 16);
                acc1 += al * __uint_as_float(b & 0xffff0000u);
            }
        }
        float alS = __expf(as_ - m) * inv;
        uint32_t b = hb[(size_t)wid * 64 + lane];
        acc0 += alS * __uint_as_float(b << 16);
        acc1 += alS * __uint_as_float(b & 0xffff0000u);
    }

    // bias + LayerNorm; lane owns dims 2*lane, 2*lane+1
    float2 bi = *(const float2*)&bias[lane * 2];
    float o0 = acc0 + bi.x, o1 = acc1 + bi.y;
    float mean = wred_sum(o0 + o1) * (1.f / 128.f);
    float d0 = o0 - mean, d1 = o1 - mean;
    float var = wred_sum(d0 * d0 + d1 * d1) * (1.f / 128.f);
    float rstd = rsqrtf(var + 1e-5f);
    float2 g = *(const float2*)&gamma[lane * 2];
    float2 be = *(const float2*)&beta[lane * 2];
    float2 o;
    o.x = d0 * rstd * g.x + be.x;
    o.y = d1 * rstd * g.y + be.y;
    *(float2*)&out[(size_t)wid * D + lane * 2] = o;
}

// ---------------- launch ----------------

extern "C" void kernel_launch(void* const* d_in, const int* in_sizes, int n_in,
                              void* d_out, int out_size, void* d_ws, size_t ws_size,
                              hipStream_t stream) {
    const float* x = (const float*)d_in[0];
    const int* ei = (const int*)d_in[1];
    const float* ea = (const float*)d_in[2];
    const float* W = (const float*)d_in[3];
    const float* att_src = (const float*)d_in[4];
    const float* att_dst = (const float*)d_in[5];
    const float* We = (const float*)d_in[6];
    const float* att_edge = (const float*)d_in[7];
    const float* bias = (const float*)d_in[8];
    const float* gamma = (const float*)d_in[9];
    const float* beta = (const float*)d_in[10];

    int N = in_sizes[0] / D;
    int E = in_sizes[1] / 2;
    const int* srcA = ei;
    const int* dstA = ei + E;

    float* p = (float*)d_ws;
    float* hbuf = p;  p += (size_t)N * D;      // f32 layer output (node_k)
    float* hsb = p;   p += N;
    float* hdb = p;   p += N;
    float* vbuf = p;  p += LNUM * D;
    float* ecp = p;   p += (size_t)LNUM * E;
    uint16_t* hbf = (uint16_t*)p; p += (size_t)N * D / 2;  // bf16 h
    int* ip = (int*)p;
    int* rowptr = ip; ip += N + 1;
    int* cnt = ip;    ip += N;
    int* colA = ip;   ip += E;
    int* pos = ip;    ip += E;

    hipMemsetAsync(cnt, 0, sizeof(int) * N, stream);
    hist_k<<<(E + 255) / 256, 256, 0, stream>>>(dstA, cnt, E);
    scan_k<<<1, 1024, 0, stream>>>(cnt, rowptr, N);
    hipMemsetAsync(cnt, 0, sizeof(int) * N, stream);
    fill_k<<<(E + 255) / 256, 256, 0, stream>>>(srcA, dstA, rowptr, cnt, colA, pos, E);
    vcomp_k<<<LNUM, D, 0, stream>>>(We, att_edge, vbuf);
    ec_k<<<(E + 31) / 32, 256, 0, stream>>>(ea, vbuf, pos, ecp, E);

    const float* hin = x;
    for (int l = 0; l < LNUM; ++l) {
        gemm_k<<<dim3((N + 63) / 64, 2), 256, 0, stream>>>(hin, W + (size_t)l * D * D, hbf, N);
        dots_k<<<(N + 3) / 4, 256, 0, stream>>>((const uint32_t*)hbf, att_src + (size_t)l * D,
                                                att_dst + (size_t)l * D, hsb, hdb, N);
        float* outp = (l == LNUM - 1) ? (float*)d_out : hbuf;
        node_k<<<(N + 3) / 4, 256, 0, stream>>>((const uint32_t*)hbf, hsb, hdb, ecp + (size_t)l * E,
                                                rowptr, colA, bias + (size_t)l * D,
                                                gamma + (size_t)l * D, beta + (size_t)l * D, outp, N);
        hin = hbuf;
    }
}

// Round 3
// 489.013 us; speedup vs baseline: 1.4011x; 1.1237x over previous
//
#include <hip/hip_runtime.h>
#include <cstdint>

#define D 128
#define LNUM 3

typedef short short8 __attribute__((ext_vector_type(8)));
typedef float f32x4 __attribute__((ext_vector_type(4)));

static __device__ __forceinline__ float wred_sum(float x) {
#pragma unroll
    for (int off = 32; off; off >>= 1) x += __shfl_xor(x, off);
    return x;
}
static __device__ __forceinline__ float wred_max(float x) {
#pragma unroll
    for (int off = 32; off; off >>= 1) x = fmaxf(x, __shfl_xor(x, off));
    return x;
}
static __device__ __forceinline__ uint32_t f2bf_rne(float x) {
    uint32_t u = __float_as_uint(x);
    uint32_t r = u + 0x7fffu + ((u >> 16) & 1u);
    return r >> 16;
}

// ---------------- CSR construction ----------------

__global__ void hist_k(const int* __restrict__ dst, int* __restrict__ cnt, int E) {
    int e = blockIdx.x * blockDim.x + threadIdx.x;
    if (e < E) atomicAdd(&cnt[dst[e]], 1);
}

__global__ __launch_bounds__(1024) void scan_k(const int* __restrict__ cnt, int* __restrict__ rowptr, int N) {
    __shared__ int sh[1024];
    int t = threadIdx.x;
    int chunk = (N + 1023) >> 10;
    int b = t * chunk;
    int e = min(b + chunk, N);
    int s = 0;
    for (int i = b; i < e; ++i) s += cnt[i];
    sh[t] = s;
    __syncthreads();
    for (int off = 1; off < 1024; off <<= 1) {
        int v = (t >= off) ? sh[t - off] : 0;
        __syncthreads();
        sh[t] += v;
        __syncthreads();
    }
    int run = sh[t] - s;  // exclusive
    for (int i = b; i < e; ++i) { rowptr[i] = run; run += cnt[i]; }
    if (t == 1023) rowptr[N] = sh[1023];
}

__global__ void fill_k(const int* __restrict__ src, const int* __restrict__ dst,
                       const int* __restrict__ rowptr, int* __restrict__ cnt,
                       int* __restrict__ colA, int* __restrict__ pos, int E) {
    int e = blockIdx.x * blockDim.x + threadIdx.x;
    if (e >= E) return;
    int d = dst[e];
    int p = atomicAdd(&cnt[d], 1);
    int q = rowptr[d] + p;
    colA[q] = src[e];
    pos[e] = q;
}

// ---------------- prep: vbuf[l] = W_e[l]@att_edge[l]; Wt[l][j][k] = bf16(W[l][k][j]) ----------------

__global__ __launch_bounds__(256) void prep_k(const float* __restrict__ We, const float* __restrict__ ae,
                                              const float* __restrict__ W, float* __restrict__ vbuf,
                                              uint16_t* __restrict__ Wt) {
    int l = blockIdx.x;
    int t = threadIdx.x;
    if (t < D) {
        const float* Wrow = We + ((size_t)l * D + t) * D;
        const float* a = ae + (size_t)l * D;
        float s = 0.f;
        for (int d = 0; d < D; ++d) s += Wrow[d] * a[d];
        vbuf[l * D + t] = s;
    }
    for (int i = t; i < D * D; i += 256) {
        int j = i >> 7, k = i & 127;
        Wt[(size_t)l * D * D + i] = (uint16_t)f2bf_rne(W[(size_t)l * D * D + (size_t)k * D + j]);
    }
}

// ---------------- x -> bf16 ----------------

__global__ __launch_bounds__(256) void cvt_k(const float* __restrict__ x, uint16_t* __restrict__ xb, int total4) {
    int i = blockIdx.x * blockDim.x + threadIdx.x;
    int stride = gridDim.x * blockDim.x;
    for (; i < total4; i += stride) {
        float4 v = *(const float4*)&x[(size_t)i * 4];
        uint2 o;
        o.x = f2bf_rne(v.x) | (f2bf_rne(v.y) << 16);
        o.y = f2bf_rne(v.z) | (f2bf_rne(v.w) << 16);
        *(uint2*)&xb[(size_t)i * 4] = o;
    }
}

// ---------------- per-edge attention scalar, permuted to CSR order ----------------

__global__ __launch_bounds__(256) void ec_k(const float* __restrict__ ea, const float* __restrict__ vbuf,
                                            const int* __restrict__ pos, float* __restrict__ ecp, int E) {
    __shared__ float vs[3][D];
    int t = threadIdx.x;
    if (t < D) {
        vs[0][t] = vbuf[t];
        vs[1][t] = vbuf[D + t];
        vs[2][t] = vbuf[2 * D + t];
    }
    __syncthreads();
    int e = blockIdx.x * 32 + (t >> 3);
    int sub = t & 7;
    if (e >= E) return;
    const float* row = ea + (size_t)e * D + sub * 16;
    float p0 = 0.f, p1 = 0.f, p2 = 0.f;
#pragma unroll
    for (int i = 0; i < 4; ++i) {
        float4 v = *(const float4*)&row[i * 4];
        int c = sub * 16 + i * 4;
        p0 += v.x * vs[0][c] + v.y * vs[0][c + 1] + v.z * vs[0][c + 2] + v.w * vs[0][c + 3];
        p1 += v.x * vs[1][c] + v.y * vs[1][c + 1] + v.z * vs[1][c + 2] + v.w * vs[1][c + 3];
        p2 += v.x * vs[2][c] + v.y * vs[2][c + 1] + v.z * vs[2][c + 2] + v.w * vs[2][c + 3];
    }
#pragma unroll
    for (int off = 1; off < 8; off <<= 1) {
        p0 += __shfl_xor(p0, off);
        p1 += __shfl_xor(p1, off);
        p2 += __shfl_xor(p2, off);
    }
    if (sub == 0) {
        int q = pos[e];
        ecp[q] = p0;
        ecp[E + q] = p1;
        ecp[2 * (size_t)E + q] = p2;
    }
}

// ---------------- MFMA GEMM: hbf = A(bf16) @ W; fused hs/hd epilogue ----------------
// A tile 64x128 staged in LDS (16B-slot XOR swizzle). B from global Wt (L2-hot).

__global__ __launch_bounds__(256) void gemm_mfma_k(const uint16_t* __restrict__ A,
                                                   const uint16_t* __restrict__ Wt,
                                                   const float* __restrict__ as_,
                                                   const float* __restrict__ ad_,
                                                   uint16_t* __restrict__ hbf,
                                                   float* __restrict__ hs, float* __restrict__ hd, int N) {
    __shared__ uint4 As[64 * 16];
    int t = threadIdx.x;
    int row0 = blockIdx.x * 64;
#pragma unroll
    for (int it = 0; it < 4; ++it) {
        int idx = it * 256 + t;
        int r = idx >> 4, s = idx & 15;
        int gr = row0 + r;
        uint4 v = make_uint4(0u, 0u, 0u, 0u);
        if (gr < N) v = *(const uint4*)&A[(size_t)gr * D + s * 8];
        As[r * 16 + (s ^ (r & 7))] = v;
    }
    __syncthreads();
    int w = t >> 6, l = t & 63;
    int lrow = l & 15, lk = l >> 4;
    int rbase = w * 16;
    short8 afrag[4];
#pragma unroll
    for (int ks = 0; ks < 4; ++ks) {
        int r = rbase + lrow;
        int s = (ks * 4 + lk) ^ (r & 7);
        afrag[ks] = __builtin_bit_cast(short8, As[r * 16 + s]);
    }
    float psum[4] = {0.f, 0.f, 0.f, 0.f}, pdum[4] = {0.f, 0.f, 0.f, 0.f};
#pragma unroll
    for (int ct = 0; ct < 8; ++ct) {
        f32x4 acc = {0.f, 0.f, 0.f, 0.f};
#pragma unroll
        for (int ks = 0; ks < 4; ++ks) {
            short8 b = *(const short8*)&Wt[(size_t)(ct * 16 + lrow) * D + ks * 32 + lk * 8];
            acc = __builtin_amdgcn_mfma_f32_16x16x32_bf16(afrag[ks], b, acc, 0, 0, 0);
        }
        int col_g = ct * 16 + lrow;
        float av = as_[col_g], dv = ad_[col_g];
#pragma unroll
        for (int r = 0; r < 4; ++r) {
            float v = acc[r];
            psum[r] += v * av;
            pdum[r] += v * dv;
            int row_g = row0 + rbase + lk * 4 + r;
            if (row_g < N) hbf[(size_t)row_g * D + col_g] = (uint16_t)f2bf_rne(v);
        }
    }
#pragma unroll
    for (int r = 0; r < 4; ++r) {
        float ps = psum[r], pd = pdum[r];
#pragma unroll
        for (int off = 1; off < 16; off <<= 1) {
            ps += __shfl_xor(ps, off);
            pd += __shfl_xor(pd, off);
        }
        if (lrow == 0) {
            int row_g = row0 + rbase + lk * 4 + r;
            if (row_g < N) { hs[row_g] = ps; hd[row_g] = pd; }
        }
    }
}

// ---------------- fused softmax + aggregate + bias + LayerNorm ----------------

__global__ __launch_bounds__(256) void node_k(const uint32_t* __restrict__ hb, const float* __restrict__ hs,
                                              const float* __restrict__ hd, const float* __restrict__ ecp,
                                              const int* __restrict__ rowptr, const int* __restrict__ colA,
                                              const float* __restrict__ bias, const float* __restrict__ gamma,
                                              const float* __restrict__ beta,
                                              uint32_t* __restrict__ outb, float* __restrict__ outf, int N) {
    __shared__ float s_al[4][66];
    __shared__ int s_co[4][66];
    int w = threadIdx.x >> 6;
    int lane = threadIdx.x & 63;
    int wid = blockIdx.x * 4 + w;
    if (wid >= N) return;
    int beg = rowptr[wid], end = rowptr[wid + 1];
    int deg = end - beg;
    float hdi = hd[wid];
    float hsi = hs[wid];
    float acc0 = 0.f, acc1 = 0.f;

    if (deg <= 63) {
        bool v = lane < deg;
        int col = v ? colA[beg + lane] : 0;
        float ec = v ? ecp[beg + lane] : 0.f;
        float a = v ? (hs[col] + hdi + ec) : -3e38f;
        a = a > 0.f ? a : 0.2f * a;
        float sumec = wred_sum(ec);
        float ecs = deg > 0 ? sumec / (float)deg : 0.f;
        float as_ = hsi + hdi + ecs;
        as_ = as_ > 0.f ? as_ : 0.2f * as_;
        float m = fmaxf(wred_max(a), as_);
        float p = __expf(a - m);
        float ps = __expf(as_ - m);
        float denom = wred_sum(p) + ps;
        float inv = 1.f / denom;
        s_al[w][lane] = p * inv;
        s_co[w][lane] = col;
        if (lane == 0) { s_al[w][deg] = ps * inv; s_co[w][deg] = wid; }
        __asm__ volatile("s_waitcnt lgkmcnt(0)" ::: "memory");
        int ne = deg + 1;
        int j = 0;
        for (; j + 4 <= ne; j += 4) {
            int c0 = s_co[w][j], c1 = s_co[w][j + 1], c2 = s_co[w][j + 2], c3 = s_co[w][j + 3];
            float a0 = s_al[w][j], a1 = s_al[w][j + 1], a2 = s_al[w][j + 2], a3 = s_al[w][j + 3];
            uint32_t b0 = hb[(size_t)c0 * 64 + lane];
            uint32_t b1 = hb[(size_t)c1 * 64 + lane];
            uint32_t b2 = hb[(size_t)c2 * 64 + lane];
            uint32_t b3 = hb[(size_t)c3 * 64 + lane];
            acc0 += a0 * __uint_as_float(b0 << 16) + a1 * __uint_as_float(b1 << 16) +
                    a2 * __uint_as_float(b2 << 16) + a3 * __uint_as_float(b3 << 16);
            acc1 += a0 * __uint_as_float(b0 & 0xffff0000u) + a1 * __uint_as_float(b1 & 0xffff0000u) +
                    a2 * __uint_as_float(b2 & 0xffff0000u) + a3 * __uint_as_float(b3 & 0xffff0000u);
        }
        for (; j < ne; ++j) {
            int c0 = s_co[w][j];
            float a0 = s_al[w][j];
            uint32_t b0 = hb[(size_t)c0 * 64 + lane];
            acc0 += a0 * __uint_as_float(b0 << 16);
            acc1 += a0 * __uint_as_float(b0 & 0xffff0000u);
        }
    } else {
        float m = -3e38f, dsum = 0.f, sumec = 0.f;
        for (int base = 0; base < deg; base += 64) {
            int j = base + lane;
            bool v = j < deg;
            int col = v ? colA[beg + j] : 0;
            float ec = v ? ecp[beg + j] : 0.f;
            float a = v ? (hs[col] + hdi + ec) : -3e38f;
            a = a > 0.f ? a : 0.2f * a;
            sumec += wred_sum(ec);
            float cm = wred_max(a);
            float nm = fmaxf(m, cm);
            dsum = dsum * __expf(m - nm) + wred_sum(__expf(a - nm));
            m = nm;
        }
        float ecs = sumec / (float)deg;
        float as_ = hsi + hdi + ecs;
        as_ = as_ > 0.f ? as_ : 0.2f * as_;
        float nm = fmaxf(m, as_);
        dsum = dsum * __expf(m - nm) + __expf(as_ - nm);
        m = nm;
        float inv = 1.f / dsum;
        for (int base = 0; base < deg; base += 64) {
            int j = base + lane;
            bool v = j < deg;
            int col = v ? colA[beg + j] : 0;
            float ec = v ? ecp[beg + j] : 0.f;
            float a = v ? (hs[col] + hdi + ec) : -3e38f;
            a = a > 0.f ? a : 0.2f * a;
            __asm__ volatile("s_waitcnt lgkmcnt(0)" ::: "memory");
            s_al[w][lane] = __expf(a - m) * inv;
            s_co[w][lane] = col;
            __asm__ volatile("s_waitcnt lgkmcnt(0)" ::: "memory");
            int cnt = min(64, deg - base);
            for (int k = 0; k < cnt; ++k) {
                int c = s_co[w][k];
                float al = s_al[w][k];
                uint32_t b = hb[(size_t)c * 64 + lane];
                acc0 += al * __uint_as_float(b << 16);
                acc1 += al * __uint_as_float(b & 0xffff0000u);
            }
        }
        float alS = __expf(as_ - m) * inv;
        uint32_t b = hb[(size_t)wid * 64 + lane];
        acc0 += alS * __uint_as_float(b << 16);
        acc1 += alS * __uint_as_float(b & 0xffff0000u);
    }

    float2 bi = *(const float2*)&bias[lane * 2];
    float o0 = acc0 + bi.x, o1 = acc1 + bi.y;
    float mean = wred_sum(o0 + o1) * (1.f / 128.f);
    float d0 = o0 - mean, d1 = o1 - mean;
    float var = wred_sum(d0 * d0 + d1 * d1) * (1.f / 128.f);
    float rstd = rsqrtf(var + 1e-5f);
    float2 g = *(const float2*)&gamma[lane * 2];
    float2 be = *(const float2*)&beta[lane * 2];
    float2 o;
    o.x = d0 * rstd * g.x + be.x;
    o.y = d1 * rstd * g.y + be.y;
    if (outf) {
        *(float2*)&outf[(size_t)wid * D + lane * 2] = o;
    } else {
        outb[(size_t)wid * 64 + lane] = f2bf_rne(o.x) | (f2bf_rne(o.y) << 16);
    }
}

// ---------------- launch ----------------

extern "C" void kernel_launch(void* const* d_in, const int* in_sizes, int n_in,
                              void* d_out, int out_size, void* d_ws, size_t ws_size,
                              hipStream_t stream) {
    const float* x = (const float*)d_in[0];
    const int* ei = (const int*)d_in[1];
    const float* ea = (const float*)d_in[2];
    const float* W = (const float*)d_in[3];
    const float* att_src = (const float*)d_in[4];
    const float* att_dst = (const float*)d_in[5];
    const float* We = (const float*)d_in[6];
    const float* att_edge = (const float*)d_in[7];
    const float* bias = (const float*)d_in[8];
    const float* gamma = (const float*)d_in[9];
    const float* beta = (const float*)d_in[10];

    int N = in_sizes[0] / D;
    int E = in_sizes[1] / 2;
    const int* srcA = ei;
    const int* dstA = ei + E;

    float* p = (float*)d_ws;
    float* hsb = p;   p += N;
    float* hdb = p;   p += N;
    float* vbuf = p;  p += LNUM * D;
    float* ecp = p;   p += (size_t)LNUM * E;
    uint16_t* xb = (uint16_t*)p;
    uint16_t* hbf = xb + (size_t)N * D;
    uint16_t* hnb = hbf + (size_t)N * D;
    uint16_t* Wt = hnb + (size_t)N * D;
    int* ip = (int*)(Wt + (size_t)LNUM * D * D);
    int* rowptr = ip; ip += N + 1;
    int* cnt = ip;    ip += N;
    int* colA = ip;   ip += E;
    int* pos = ip;    ip += E;

    hipMemsetAsync(cnt, 0, sizeof(int) * N, stream);
    hist_k<<<(E + 255) / 256, 256, 0, stream>>>(dstA, cnt, E);
    scan_k<<<1, 1024, 0, stream>>>(cnt, rowptr, N);
    hipMemsetAsync(cnt, 0, sizeof(int) * N, stream);
    fill_k<<<(E + 255) / 256, 256, 0, stream>>>(srcA, dstA, rowptr, cnt, colA, pos, E);
    prep_k<<<LNUM, 256, 0, stream>>>(We, att_edge, W, vbuf, Wt);
    ec_k<<<(E + 31) / 32, 256, 0, stream>>>(ea, vbuf, pos, ecp, E);
    cvt_k<<<2048, 256, 0, stream>>>(x, xb, N * D / 4);

    const uint16_t* hin = xb;
    for (int l = 0; l < LNUM; ++l) {
        gemm_mfma_k<<<(N + 63) / 64, 256, 0, stream>>>(hin, Wt + (size_t)l * D * D,
                                                       att_src + (size_t)l * D, att_dst + (size_t)l * D,
                                                       hbf, hsb, hdb, N);
        bool last = (l == LNUM - 1);
        node_k<<<(N + 3) / 4, 256, 0, stream>>>((const uint32_t*)hbf, hsb, hdb, ecp + (size_t)l * E,
                                                rowptr, colA, bias + (size_t)l * D,
                                                gamma + (size_t)l * D, beta + (size_t)l * D,
                                                last ? nullptr : (uint32_t*)hnb,
                                                last ? (float*)d_out : nullptr, N);
        hin = hnb;
    }
}

// Round 4
// 431.351 us; speedup vs baseline: 1.5884x; 1.1337x over previous
//
#include <hip/hip_runtime.h>
#include <cstdint>

#define D 128
#define LNUM 3

typedef short short8 __attribute__((ext_vector_type(8)));
typedef float f32x4 __attribute__((ext_vector_type(4)));

static __device__ __forceinline__ float wred_sum(float x) {
#pragma unroll
    for (int off = 32; off; off >>= 1) x += __shfl_xor(x, off);
    return x;
}
static __device__ __forceinline__ float wred_max(float x) {
#pragma unroll
    for (int off = 32; off; off >>= 1) x = fmaxf(x, __shfl_xor(x, off));
    return x;
}
static __device__ __forceinline__ uint32_t f2bf_rne(float x) {
    uint32_t u = __float_as_uint(x);
    uint32_t r = u + 0x7fffu + ((u >> 16) & 1u);
    return r >> 16;
}

// ---------------- pre: Wt transpose->bf16, vbuf = We@ae, x->bf16, hist ----------------

__global__ __launch_bounds__(256) void pre_k(const float* __restrict__ W, const float* __restrict__ We,
                                             const float* __restrict__ ae, const float* __restrict__ x,
                                             const int* __restrict__ dst,
                                             uint16_t* __restrict__ Wt, float* __restrict__ vbuf,
                                             uint16_t* __restrict__ xb, int* __restrict__ cnt,
                                             int ND4, int E) {
    int tid = blockIdx.x * 256 + threadIdx.x;
    int stride = gridDim.x * 256;
    // x -> bf16 (float4 granularity)
    for (int i = tid; i < ND4; i += stride) {
        float4 v = *(const float4*)&x[(size_t)i * 4];
        uint2 o;
        o.x = f2bf_rne(v.x) | (f2bf_rne(v.y) << 16);
        o.y = f2bf_rne(v.z) | (f2bf_rne(v.w) << 16);
        *(uint2*)&xb[(size_t)i * 4] = o;
    }
    // degree histogram
    for (int e = tid; e < E; e += stride) atomicAdd(&cnt[dst[e]], 1);
    // Wt[l][j][k] = bf16(W[l][k][j])
    for (int i = tid; i < LNUM * D * D; i += stride) {
        int l = i >> 14;
        int r = i & (D * D - 1);
        int j = r >> 7, k = r & 127;
        Wt[i] = (uint16_t)f2bf_rne(W[(size_t)l * D * D + (size_t)k * D + j]);
    }
    // vbuf[l][j] = sum_d We[l][j][d]*ae[l][d]
    if (tid < LNUM * D) {
        int l = tid >> 7, j = tid & 127;
        const float* Wrow = We + ((size_t)l * D + j) * D;
        const float* a = ae + (size_t)l * D;
        float s = 0.f;
        for (int d = 0; d < D; ++d) s += Wrow[d] * a[d];
        vbuf[tid] = s;
    }
}

// ---------------- exclusive scan of cnt -> rowptr ----------------

__global__ __launch_bounds__(1024) void scan_k(const int* __restrict__ cnt, int* __restrict__ rowptr, int N) {
    __shared__ int sh[1024];
    int t = threadIdx.x;
    int chunk = (N + 1023) >> 10;
    int b = t * chunk;
    int e = min(b + chunk, N);
    int s = 0;
    for (int i = b; i < e; ++i) s += cnt[i];
    sh[t] = s;
    __syncthreads();
    for (int off = 1; off < 1024; off <<= 1) {
        int v = (t >= off) ? sh[t - off] : 0;
        __syncthreads();
        sh[t] += v;
        __syncthreads();
    }
    int run = sh[t] - s;  // exclusive
    for (int i = b; i < e; ++i) { rowptr[i] = run; run += cnt[i]; }
    if (t == 1023) rowptr[N] = sh[1023];
}

// ---------------- fused CSR fill + edge-attr contraction; one 16B record per edge ----------------
// rec[q] = { src, bf(ec0), bf(ec1), bf(ec2) } at CSR slot q (ec stored as f32 bits)

__global__ __launch_bounds__(256) void fillec_k(const float* __restrict__ ea, const float* __restrict__ vbuf,
                                                const int* __restrict__ src, const int* __restrict__ dst,
                                                const int* __restrict__ rowptr, int* __restrict__ cnt,
                                                uint4* __restrict__ rec, int E) {
    __shared__ float vs[3][D];
    int t = threadIdx.x;
    if (t < D) {
        vs[0][t] = vbuf[t];
        vs[1][t] = vbuf[D + t];
        vs[2][t] = vbuf[2 * D + t];
    }
    __syncthreads();
    int e = blockIdx.x * 32 + (t >> 3);
    int sub = t & 7;
    if (e >= E) return;
    const float* row = ea + (size_t)e * D + sub * 16;
    float p0 = 0.f, p1 = 0.f, p2 = 0.f;
#pragma unroll
    for (int i = 0; i < 4; ++i) {
        float4 v = *(const float4*)&row[i * 4];
        int c = sub * 16 + i * 4;
        p0 += v.x * vs[0][c] + v.y * vs[0][c + 1] + v.z * vs[0][c + 2] + v.w * vs[0][c + 3];
        p1 += v.x * vs[1][c] + v.y * vs[1][c + 1] + v.z * vs[1][c + 2] + v.w * vs[1][c + 3];
        p2 += v.x * vs[2][c] + v.y * vs[2][c + 1] + v.z * vs[2][c + 2] + v.w * vs[2][c + 3];
    }
#pragma unroll
    for (int off = 1; off < 8; off <<= 1) {
        p0 += __shfl_xor(p0, off);
        p1 += __shfl_xor(p1, off);
        p2 += __shfl_xor(p2, off);
    }
    if (sub == 0) {
        int d = dst[e];
        int p = atomicSub(&cnt[d], 1) - 1;   // counts back down to 0; slot within row
        int q = rowptr[d] + p;
        uint4 r;
        r.x = (uint32_t)src[e];
        r.y = __float_as_uint(p0);
        r.z = __float_as_uint(p1);
        r.w = __float_as_uint(p2);
        rec[q] = r;
    }
}

// ---------------- MFMA GEMM: hbf = A(bf16) @ W; fused hs/hd epilogue ----------------

__global__ __launch_bounds__(256) void gemm_mfma_k(const uint16_t* __restrict__ A,
                                                   const uint16_t* __restrict__ Wt,
                                                   const float* __restrict__ as_,
                                                   const float* __restrict__ ad_,
                                                   uint16_t* __restrict__ hbf,
                                                   float* __restrict__ hs, float* __restrict__ hd, int N) {
    __shared__ uint4 As[64 * 16];
    int t = threadIdx.x;
    int row0 = blockIdx.x * 64;
#pragma unroll
    for (int it = 0; it < 4; ++it) {
        int idx = it * 256 + t;
        int r = idx >> 4, s = idx & 15;
        int gr = row0 + r;
        uint4 v = make_uint4(0u, 0u, 0u, 0u);
        if (gr < N) v = *(const uint4*)&A[(size_t)gr * D + s * 8];
        As[r * 16 + (s ^ (r & 7))] = v;
    }
    __syncthreads();
    int w = t >> 6, l = t & 63;
    int lrow = l & 15, lk = l >> 4;
    int rbase = w * 16;
    short8 afrag[4];
#pragma unroll
    for (int ks = 0; ks < 4; ++ks) {
        int r = rbase + lrow;
        int s = (ks * 4 + lk) ^ (r & 7);
        afrag[ks] = __builtin_bit_cast(short8, As[r * 16 + s]);
    }
    float psum[4] = {0.f, 0.f, 0.f, 0.f}, pdum[4] = {0.f, 0.f, 0.f, 0.f};
#pragma unroll
    for (int ct = 0; ct < 8; ++ct) {
        f32x4 acc = {0.f, 0.f, 0.f, 0.f};
#pragma unroll
        for (int ks = 0; ks < 4; ++ks) {
            short8 b = *(const short8*)&Wt[(size_t)(ct * 16 + lrow) * D + ks * 32 + lk * 8];
            acc = __builtin_amdgcn_mfma_f32_16x16x32_bf16(afrag[ks], b, acc, 0, 0, 0);
        }
        int col_g = ct * 16 + lrow;
        float av = as_[col_g], dv = ad_[col_g];
#pragma unroll
        for (int r = 0; r < 4; ++r) {
            float v = acc[r];
            psum[r] += v * av;
            pdum[r] += v * dv;
            int row_g = row0 + rbase + lk * 4 + r;
            if (row_g < N) hbf[(size_t)row_g * D + col_g] = (uint16_t)f2bf_rne(v);
        }
    }
#pragma unroll
    for (int r = 0; r < 4; ++r) {
        float ps = psum[r], pd = pdum[r];
#pragma unroll
        for (int off = 1; off < 16; off <<= 1) {
            ps += __shfl_xor(ps, off);
            pd += __shfl_xor(pd, off);
        }
        if (lrow == 0) {
            int row_g = row0 + rbase + lk * 4 + r;
            if (row_g < N) { hs[row_g] = ps; hd[row_g] = pd; }
        }
    }
}

// ---------------- fused softmax + aggregate + bias + LayerNorm ----------------

__global__ __launch_bounds__(256) void node_k(const uint32_t* __restrict__ hb, const float* __restrict__ hs,
                                              const float* __restrict__ hd, const uint4* __restrict__ rec,
                                              const int* __restrict__ rowptr,
                                              const float* __restrict__ bias, const float* __restrict__ gamma,
                                              const float* __restrict__ beta,
                                              uint32_t* __restrict__ outb, float* __restrict__ outf,
                                              int N, int lsel) {
    __shared__ float s_al[4][66];
    __shared__ int s_co[4][66];
    int w = threadIdx.x >> 6;
    int lane = threadIdx.x & 63;
    int wid = blockIdx.x * 4 + w;
    if (wid >= N) return;
    int beg = rowptr[wid], end = rowptr[wid + 1];
    int deg = end - beg;
    float hdi = hd[wid];
    float hsi = hs[wid];
    float acc0 = 0.f, acc1 = 0.f;

    if (deg <= 63) {
        bool v = lane < deg;
        uint4 r = v ? rec[beg + lane] : make_uint4(0u, 0u, 0u, 0u);
        int col = (int)r.x;
        uint32_t ecu = lsel == 0 ? r.y : (lsel == 1 ? r.z : r.w);
        float ec = __uint_as_float(ecu);
        float a = v ? (hs[col] + hdi + ec) : -3e38f;
        a = a > 0.f ? a : 0.2f * a;
        float sumec = wred_sum(v ? ec : 0.f);
        float ecs = deg > 0 ? sumec / (float)deg : 0.f;
        float as_ = hsi + hdi + ecs;
        as_ = as_ > 0.f ? as_ : 0.2f * as_;
        float m = fmaxf(wred_max(a), as_);
        float p = __expf(a - m);
        float ps = __expf(as_ - m);
        float denom = wred_sum(p) + ps;
        float inv = 1.f / denom;
        s_al[w][lane] = p * inv;
        s_co[w][lane] = col;
        if (lane == 0) { s_al[w][deg] = ps * inv; s_co[w][deg] = wid; }
        __asm__ volatile("s_waitcnt lgkmcnt(0)" ::: "memory");
        int ne = deg + 1;
        int j = 0;
        for (; j + 4 <= ne; j += 4) {
            int c0 = s_co[w][j], c1 = s_co[w][j + 1], c2 = s_co[w][j + 2], c3 = s_co[w][j + 3];
            float a0 = s_al[w][j], a1 = s_al[w][j + 1], a2 = s_al[w][j + 2], a3 = s_al[w][j + 3];
            uint32_t b0 = hb[(size_t)c0 * 64 + lane];
            uint32_t b1 = hb[(size_t)c1 * 64 + lane];
            uint32_t b2 = hb[(size_t)c2 * 64 + lane];
            uint32_t b3 = hb[(size_t)c3 * 64 + lane];
            acc0 += a0 * __uint_as_float(b0 << 16) + a1 * __uint_as_float(b1 << 16) +
                    a2 * __uint_as_float(b2 << 16) + a3 * __uint_as_float(b3 << 16);
            acc1 += a0 * __uint_as_float(b0 & 0xffff0000u) + a1 * __uint_as_float(b1 & 0xffff0000u) +
                    a2 * __uint_as_float(b2 & 0xffff0000u) + a3 * __uint_as_float(b3 & 0xffff0000u);
        }
        for (; j < ne; ++j) {
            int c0 = s_co[w][j];
            float a0 = s_al[w][j];
            uint32_t b0 = hb[(size_t)c0 * 64 + lane];
            acc0 += a0 * __uint_as_float(b0 << 16);
            acc1 += a0 * __uint_as_float(b0 & 0xffff0000u);
        }
    } else {
        float m = -3e38f, dsum = 0.f, sumec = 0.f;
        for (int base = 0; base < deg; base += 64) {
            int jj = base + lane;
            bool v = jj < deg;
            uint4 r = v ? rec[beg + jj] : make_uint4(0u, 0u, 0u, 0u);
            uint32_t ecu = lsel == 0 ? r.y : (lsel == 1 ? r.z : r.w);
            float ec = __uint_as_float(ecu);
            float a = v ? (hs[(int)r.x] + hdi + ec) : -3e38f;
            a = a > 0.f ? a : 0.2f * a;
            sumec += wred_sum(v ? ec : 0.f);
            float cm = wred_max(a);
            float nm = fmaxf(m, cm);
            dsum = dsum * __expf(m - nm) + wred_sum(__expf(a - nm));
            m = nm;
        }
        float ecs = sumec / (float)deg;
        float as_ = hsi + hdi + ecs;
        as_ = as_ > 0.f ? as_ : 0.2f * as_;
        float nm = fmaxf(m, as_);
        dsum = dsum * __expf(m - nm) + __expf(as_ - nm);
        m = nm;
        float inv = 1.f / dsum;
        for (int base = 0; base < deg; base += 64) {
            int jj = base + lane;
            bool v = jj < deg;
            uint4 r = v ? rec[beg + jj] : make_uint4(0u, 0u, 0u, 0u);
            int col = (int)r.x;
            uint32_t ecu = lsel == 0 ? r.y : (lsel == 1 ? r.z : r.w);
            float ec = __uint_as_float(ecu);
            float a = v ? (hs[col] + hdi + ec) : -3e38f;
            a = a > 0.f ? a : 0.2f * a;
            __asm__ volatile("s_waitcnt lgkmcnt(0)" ::: "memory");
            s_al[w][lane] = __expf(a - m) * inv;
            s_co[w][lane] = col;
            __asm__ volatile("s_waitcnt lgkmcnt(0)" ::: "memory");
            int cnt = min(64, deg - base);
            for (int k = 0; k < cnt; ++k) {
                int c = s_co[w][k];
                float al = s_al[w][k];
                uint32_t b = hb[(size_t)c * 64 + lane];
                acc0 += al * __uint_as_float(b << 16);
                acc1 += al * __uint_as_float(b & 0xffff0000u);
            }
        }
        float alS = __expf(as_ - m) * inv;
        uint32_t b = hb[(size_t)wid * 64 + lane];
        acc0 += alS * __uint_as_float(b << 16);
        acc1 += alS * __uint_as_float(b & 0xffff0000u);
    }

    float2 bi = *(const float2*)&bias[lane * 2];
    float o0 = acc0 + bi.x, o1 = acc1 + bi.y;
    float mean = wred_sum(o0 + o1) * (1.f / 128.f);
    float d0 = o0 - mean, d1 = o1 - mean;
    float var = wred_sum(d0 * d0 + d1 * d1) * (1.f / 128.f);
    float rstd = rsqrtf(var + 1e-5f);
    float2 g = *(const float2*)&gamma[lane * 2];
    float2 be = *(const float2*)&beta[lane * 2];
    float2 o;
    o.x = d0 * rstd * g.x + be.x;
    o.y = d1 * rstd * g.y + be.y;
    if (outf) {
        *(float2*)&outf[(size_t)wid * D + lane * 2] = o;
    } else {
        outb[(size_t)wid * 64 + lane] = f2bf_rne(o.x) | (f2bf_rne(o.y) << 16);
    }
}

// ---------------- launch ----------------

extern "C" void kernel_launch(void* const* d_in, const int* in_sizes, int n_in,
                              void* d_out, int out_size, void* d_ws, size_t ws_size,
                              hipStream_t stream) {
    const float* x = (const float*)d_in[0];
    const int* ei = (const int*)d_in[1];
    const float* ea = (const float*)d_in[2];
    const float* W = (const float*)d_in[3];
    const float* att_src = (const float*)d_in[4];
    const float* att_dst = (const float*)d_in[5];
    const float* We = (const float*)d_in[6];
    const float* att_edge = (const float*)d_in[7];
    const float* bias = (const float*)d_in[8];
    const float* gamma = (const float*)d_in[9];
    const float* beta = (const float*)d_in[10];

    int N = in_sizes[0] / D;
    int E = in_sizes[1] / 2;
    const int* srcA = ei;
    const int* dstA = ei + E;

    float* p = (float*)d_ws;
    float* hsb = p;   p += N;
    float* hdb = p;   p += N;
    float* vbuf = p;  p += LNUM * D;
    uint16_t* xb = (uint16_t*)p;
    uint16_t* hbf = xb + (size_t)N * D;
    uint16_t* hnb = hbf + (size_t)N * D;
    uint16_t* Wt = hnb + (size_t)N * D;
    uint4* rec = (uint4*)(Wt + (size_t)LNUM * D * D);
    int* ip = (int*)(rec + E);
    int* rowptr = ip; ip += N + 1;
    int* cnt = ip;    ip += N;

    hipMemsetAsync(cnt, 0, sizeof(int) * N, stream);
    pre_k<<<1536, 256, 0, stream>>>(W, We, att_edge, x, dstA, Wt, vbuf, xb, cnt, N * D / 4, E);
    scan_k<<<1, 1024, 0, stream>>>(cnt, rowptr, N);
    fillec_k<<<(E + 31) / 32, 256, 0, stream>>>(ea, vbuf, srcA, dstA, rowptr, cnt, rec, E);

    const uint16_t* hin = xb;
    for (int l = 0; l < LNUM; ++l) {
        gemm_mfma_k<<<(N + 63) / 64, 256, 0, stream>>>(hin, Wt + (size_t)l * D * D,
                                                       att_src + (size_t)l * D, att_dst + (size_t)l * D,
                                                       hbf, hsb, hdb, N);
        bool last = (l == LNUM - 1);
        node_k<<<(N + 3) / 4, 256, 0, stream>>>((const uint32_t*)hbf, hsb, hdb, rec, rowptr,
                                                bias + (size_t)l * D, gamma + (size_t)l * D,
                                                beta + (size_t)l * D,
                                                last ? nullptr : (uint32_t*)hnb,
                                                last ? (float*)d_out : nullptr, N, l);
        hin = hnb;
    }
}